// Round 18
// baseline (159.169 us; speedup 1.0000x reference)
//
#include <hip/hip_runtime.h>
#include <stdint.h>

typedef int i32x4  __attribute__((ext_vector_type(4)));
typedef int i32x16 __attribute__((ext_vector_type(16)));

static constexpr int Mdim   = 16384;     // B*S = 8*2048
static constexpr int Kdim   = 2048;      // D_IN
static constexpr int Ndim   = 2048;      // D_OUT
static constexpr int WELEMS = Ndim * Kdim;   // 4194304

// Fragment-major pack layout (shared by packers and GEMM):
//   chunk(R, c) = 1024 B at base + (R*64 + c)*1024
//   byte l*16 + b of a chunk holds row R*32 + (l&31), k = c*32 + (l>>5)*16 + b

// ---------------- async global->LDS (16B per lane, lane-ordered dest) -------
__device__ __forceinline__ void gload_lds16(const void* g, void* l) {
  __builtin_amdgcn_global_load_lds(
      (const __attribute__((address_space(1))) void*)g,
      (__attribute__((address_space(3))) void*)l,
      16, 0, 0);
}

// ---------------- K1: partial sums of |w| -----------------------------------
__global__ void k_abs_part(const float* __restrict__ w, float* __restrict__ part) {
  const float4* w4 = (const float4*)w;
  float s = 0.f;
  int idx = blockIdx.x * 256 + threadIdx.x;
  #pragma unroll 4
  for (int i = idx; i < WELEMS / 4; i += 256 * 256) {
    float4 v = w4[i];
    s += fabsf(v.x) + fabsf(v.y) + fabsf(v.z) + fabsf(v.w);
  }
  #pragma unroll
  for (int off = 32; off > 0; off >>= 1) s += __shfl_down(s, off);
  __shared__ float sm[4];
  if ((threadIdx.x & 63) == 0) sm[threadIdx.x >> 6] = s;
  __syncthreads();
  if (threadIdx.x == 0) part[blockIdx.x] = sm[0] + sm[1] + sm[2] + sm[3];
}

// ---------------- K2: finalize scale = mean(|w|) ----------------------------
__global__ void k_abs_final(const float* __restrict__ part, float* __restrict__ scal) {
  float s = part[threadIdx.x];           // exactly 256 partials, block = 256
  #pragma unroll
  for (int off = 32; off > 0; off >>= 1) s += __shfl_down(s, off);
  __shared__ float sm[4];
  if ((threadIdx.x & 63) == 0) sm[threadIdx.x >> 6] = s;
  __syncthreads();
  if (threadIdx.x == 0) scal[0] = (sm[0] + sm[1] + sm[2] + sm[3]) / (float)WELEMS;
}

__device__ __forceinline__ int quant4(float4 v, float sc) {
  int a = (int)rintf(v.x / sc); a = a < -128 ? -128 : (a > 127 ? 127 : a);
  int b = (int)rintf(v.y / sc); b = b < -128 ? -128 : (b > 127 ? 127 : b);
  int c = (int)rintf(v.z / sc); c = c < -128 ? -128 : (c > 127 ? 127 : c);
  int d = (int)rintf(v.w / sc); d = d < -128 ? -128 : (d > 127 ? 127 : d);
  return (a & 255) | ((b & 255) << 8) | ((c & 255) << 16) | ((d & 255) << 24);
}

__device__ __forceinline__ int tern4(float4 v, float s) {
  int a = (int)rintf(v.x / s); a = a < -1 ? -1 : (a > 1 ? 1 : a);
  int b = (int)rintf(v.y / s); b = b < -1 ? -1 : (b > 1 ? 1 : b);
  int c = (int)rintf(v.z / s); c = c < -1 ? -1 : (c > 1 ? 1 : c);
  int d = (int)rintf(v.w / s); d = d < -1 ? -1 : (d > 1 ? 1 : d);
  return (a & 255) | ((b & 255) << 8) | ((c & 255) << 16) | ((d & 255) << 24);
}

// LDS row stride for the transpose buffers: 2052 B (513 dwords, odd ->
// bank = (l*513 + k)%32 spreads 32 rows over all 32 banks; <=2-way = free).
static constexpr int LSTR = 2052;

// ---------------- K3: ternary weight quantize + fragment-major pack ---------
__global__ __launch_bounds__(512) void k_wquant(const float* __restrict__ w,
                                                char* __restrict__ wq,
                                                const float* __restrict__ scal) {
  __shared__ char sq[32 * LSTR];
  const float s  = scal[0] + 1e-8f;
  const int   Rg = blockIdx.x;
  const int   wv = threadIdx.x >> 6;     // 0..7
  const int   l  = threadIdx.x & 63;

  #pragma unroll
  for (int it = 0; it < 4; ++it) {
    const int rs = it * 8 + wv;          // row slot 0..31
    const float4* wr = (const float4*)(w + (size_t)(Rg * 32 + rs) * Kdim);
    #pragma unroll
    for (int c = 0; c < 8; ++c)
      *(int*)(&sq[rs * LSTR + (c * 64 + l) * 4]) = tern4(wr[c * 64 + l], s);
  }
  __syncthreads();
  char* dst = wq + (size_t)Rg * 65536;
  #pragma unroll
  for (int i = 0; i < 8; ++i) {
    const int c = i * 8 + wv;            // chunk 0..63
    int p[4];
    #pragma unroll
    for (int j = 0; j < 4; ++j)
      p[j] = *(const int*)(&sq[(l & 31) * LSTR + c * 32 + (l >> 5) * 16 + j * 4]);
    *(int4*)(dst + c * 1024 + l * 16) = make_int4(p[0], p[1], p[2], p[3]);
  }
}

// ---------------- K4: per-row absmax + int8 quantize + pack -----------------
__global__ __launch_bounds__(512) void k_xquant(const float* __restrict__ x,
                                                char* __restrict__ xq,
                                                float* __restrict__ xs) {
  __shared__ char sq[32 * LSTR];
  const int Rg = blockIdx.x;
  const int wv = threadIdx.x >> 6;       // 0..7
  const int l  = threadIdx.x & 63;

  #pragma unroll
  for (int it = 0; it < 4; ++it) {
    const int rs  = it * 8 + wv;
    const int row = Rg * 32 + rs;
    const float4* xr = (const float4*)(x + (size_t)row * Kdim);
    float4 v[8];
    float  m = 0.f;
    #pragma unroll
    for (int c = 0; c < 8; ++c) {
      v[c] = xr[c * 64 + l];
      m = fmaxf(m, fmaxf(fmaxf(fabsf(v[c].x), fabsf(v[c].y)),
                         fmaxf(fabsf(v[c].z), fabsf(v[c].w))));
    }
    #pragma unroll
    for (int off = 1; off < 64; off <<= 1) m = fmaxf(m, __shfl_xor(m, off));
    m = fmaxf(m, 1e-8f);
    const float sc = m / 127.0f;
    if (l == 0) xs[row] = sc;
    #pragma unroll
    for (int c = 0; c < 8; ++c)
      *(int*)(&sq[rs * LSTR + (c * 64 + l) * 4]) = quant4(v[c], sc);
  }
  __syncthreads();
  char* dst = xq + (size_t)Rg * 65536;
  #pragma unroll
  for (int i = 0; i < 8; ++i) {
    const int c = i * 8 + wv;
    int p[4];
    #pragma unroll
    for (int j = 0; j < 4; ++j)
      p[j] = *(const int*)(&sq[(l & 31) * LSTR + c * 32 + (l >> 5) * 16 + j * 4]);
    *(int4*)(dst + c * 1024 + l * 16) = make_int4(p[0], p[1], p[2], p[3]);
  }
}

// ---------------- K5: int8 MFMA GEMM, 128x128 tile, 2-wave blocks -----------
// out = (scale*xs[m]) * (xq . wq^T) + bias
// 128 threads = 2 waves; wave tile 64x128 = acc[2][4] of 32x32 mfma
// -> 12 ds_reads feed 16 MFMAs (ratio 1.33 vs R17's 1.0), LDS/epoch -17%.
// Ring-2 LDS = 32 KiB, launch_bounds(128,2) (VGPR<=256, 2 waves/SIMD)
// -> 4 co-resident blocks/CU = 4 independent barrier domains (R17's win).
// Per tile: {vmcnt(8); bar; ds_read 12 x b128; bar; STAGE(t+2); setprio MFMA}.
// Per-wave 8 staging gloads/tile: vmcnt(8) leaves t+1's 8 in flight; never 0
// until the peeled last tile.
__global__ __launch_bounds__(128, 2) void k_gemm(
    const char* __restrict__ xq, const char* __restrict__ wq,
    const float* __restrict__ xs, const float* __restrict__ scal,
    const float* __restrict__ bias, float* __restrict__ out) {
  __shared__ __attribute__((aligned(128))) char lds[2][16384];

  // XCD-aware bijective swizzle: 2048 blocks, 2048 % 8 == 0.
  const int hw  = blockIdx.x;
  const int lin = (hw & 7) * 256 + (hw >> 3);
  const int bm  = lin >> 4;               // 128 M-tiles
  const int bn  = lin & 15;               // 16 N-tiles

  const int tid = threadIdx.x;
  const int w   = tid >> 6;               // wave 0..1 (row half)
  const int l   = tid & 63;
  const int l16 = l * 16;

  // staging: wave w stages A rgroups {2w, 2w+1} and B rgroups {2w, 2w+1}
  const char* gA = xq + (size_t)(bm * 4 + 2 * w) * 65536 + l16;
  const char* gB = wq + (size_t)(bn * 4 + 2 * w) * 65536 + l16;
  const int   w4k = w * 4096;             // (2w)*2*1024

#define STAGE(t_)                                                         \
  { char* sb = &lds[(t_) & 1][0]; const int kb_ = (t_) * 2048;            \
    gload_lds16(gA + kb_,                sb + w4k);                       \
    gload_lds16(gA + kb_ + 1024,         sb + w4k + 1024);                \
    gload_lds16(gA + 65536 + kb_,        sb + w4k + 2048);                \
    gload_lds16(gA + 65536 + kb_ + 1024, sb + w4k + 3072);                \
    gload_lds16(gB + kb_,                sb + 8192 + w4k);                \
    gload_lds16(gB + kb_ + 1024,         sb + 8192 + w4k + 1024);         \
    gload_lds16(gB + 65536 + kb_,        sb + 8192 + w4k + 2048);         \
    gload_lds16(gB + 65536 + kb_ + 1024, sb + 8192 + w4k + 3072); }

  i32x16 acc[2][4] = {};

  STAGE(0); STAGE(1);                     // 16 per-wave loads in flight

#define TILE(T_, VMTOK, DOSTG)                                              \
  {                                                                         \
    VMTOK                                                                   \
    __builtin_amdgcn_s_barrier();                                           \
    asm volatile("" ::: "memory");                                          \
    const char* base_ = &lds[(T_) & 1][0];                                  \
    i32x4 aF[2][2], bF[4][2];                                               \
    _Pragma("unroll") for (int mi = 0; mi < 2; ++mi)                        \
      _Pragma("unroll") for (int ks = 0; ks < 2; ++ks)                      \
        aF[mi][ks] = *(const i32x4*)(base_ + ((2*w+mi)*2+ks)*1024 + l16);   \
    _Pragma("unroll") for (int ni = 0; ni < 4; ++ni)                        \
      _Pragma("unroll") for (int ks = 0; ks < 2; ++ks)                      \
        bF[ni][ks] = *(const i32x4*)(base_ + 8192 + (ni*2+ks)*1024 + l16);  \
    __builtin_amdgcn_s_barrier();                                           \
    asm volatile("" ::: "memory");                                          \
    if (DOSTG) STAGE((T_) + 2)                                              \
    __builtin_amdgcn_s_setprio(1);                                          \
    _Pragma("unroll") for (int ks = 0; ks < 2; ++ks)                        \
      _Pragma("unroll") for (int mi = 0; mi < 2; ++mi)                      \
        _Pragma("unroll") for (int ni = 0; ni < 4; ++ni)                    \
          acc[mi][ni] = __builtin_amdgcn_mfma_i32_32x32x32_i8(              \
              aF[mi][ks], bF[ni][ks], acc[mi][ni], 0, 0, 0);                \
    __builtin_amdgcn_s_setprio(0);                                          \
  }

#define VM8  asm volatile("s_waitcnt vmcnt(8)" ::: "memory");
#define VM0  asm volatile("s_waitcnt vmcnt(0)" ::: "memory");

  #pragma unroll 2
  for (int t = 0; t < 30; ++t)            // uniform: confirm t, stage t+2
    TILE(t, VM8, 1)
  TILE(30, VM8, 0)                        // tile 31's 8 loads stay in flight
  TILE(31, VM0, 0)                        // queue empties (last tile only)
#undef TILE
#undef STAGE
#undef VM8
#undef VM0

  // epilogue: C/D mapping col = lane&31, row = (r&3) + 8*(r>>2) + 4*(lane>>5)
  const float wsc = scal[0];
  const int   lhi = (l >> 5) * 4, lcol = l & 31;
  float bc[4];
  #pragma unroll
  for (int ni = 0; ni < 4; ++ni)
    bc[ni] = bias[bn * 128 + ni * 32 + lcol];

  #pragma unroll
  for (int mi = 0; mi < 2; ++mi) {
    const int rb = bm * 128 + w * 64 + mi * 32 + lhi;
    #pragma unroll
    for (int r = 0; r < 16; ++r) {
      const int   row = rb + (r & 3) + 8 * (r >> 2);
      const float sv  = wsc * xs[row];
      #pragma unroll
      for (int ni = 0; ni < 4; ++ni) {
        const int col = bn * 128 + ni * 32 + lcol;
        out[(size_t)row * Ndim + col] = (float)acc[mi][ni][r] * sv + bc[ni];
      }
    }
  }
}

// ---------------- launch -----------------------------------------------------
extern "C" void kernel_launch(void* const* d_in, const int* in_sizes, int n_in,
                              void* d_out, int out_size, void* d_ws, size_t ws_size,
                              hipStream_t stream) {
  const float* x    = (const float*)d_in[0];
  const float* wgt  = (const float*)d_in[1];
  const float* bias = (const float*)d_in[2];
  float* out = (float*)d_out;

  float* ws_f = (float*)d_ws;
  float* scal = ws_f;               // 1 float
  float* part = ws_f + 64;          // 256 floats
  float* xs   = ws_f + 1024;        // 16384 floats
  char*  wq   = (char*)(ws_f + 20480);          // 4 MiB packed, 16B-aligned
  char*  xq   = wq + (size_t)WELEMS;            // 32 MiB packed, 16B-aligned

  hipLaunchKernelGGL(k_abs_part,  dim3(256),      dim3(256), 0, stream, wgt, part);
  hipLaunchKernelGGL(k_abs_final, dim3(1),        dim3(256), 0, stream, part, scal);
  hipLaunchKernelGGL(k_wquant,    dim3(64),       dim3(512), 0, stream, wgt, wq, scal);
  hipLaunchKernelGGL(k_xquant,    dim3(Mdim/32),  dim3(512), 0, stream, x, xq, xs);
  hipLaunchKernelGGL(k_gemm,      dim3((Mdim/128)*(Ndim/128)), dim3(128), 0, stream,
                     xq, wq, xs, scal, bias, out);
}

// Round 19
// 146.773 us; speedup vs baseline: 1.0845x; 1.0845x over previous
//
#include <hip/hip_runtime.h>
#include <stdint.h>

typedef int i32x4  __attribute__((ext_vector_type(4)));
typedef int i32x16 __attribute__((ext_vector_type(16)));

static constexpr int Mdim   = 16384;     // B*S = 8*2048
static constexpr int Kdim   = 2048;      // D_IN
static constexpr int Ndim   = 2048;      // D_OUT
static constexpr int WELEMS = Ndim * Kdim;   // 4194304

// Fragment-major pack layout (shared by packers and GEMM):
//   chunk(R, c) = 1024 B at base + (R*64 + c)*1024
//   byte l*16 + b of a chunk holds row R*32 + (l&31), k = c*32 + (l>>5)*16 + b

// ---------------- async global->LDS (16B per lane, lane-ordered dest) -------
__device__ __forceinline__ void gload_lds16(const void* g, void* l) {
  __builtin_amdgcn_global_load_lds(
      (const __attribute__((address_space(1))) void*)g,
      (__attribute__((address_space(3))) void*)l,
      16, 0, 0);
}

// ---------------- K1: partial sums of |w| -----------------------------------
__global__ void k_abs_part(const float* __restrict__ w, float* __restrict__ part) {
  const float4* w4 = (const float4*)w;
  float s = 0.f;
  int idx = blockIdx.x * 256 + threadIdx.x;
  #pragma unroll 4
  for (int i = idx; i < WELEMS / 4; i += 256 * 256) {
    float4 v = w4[i];
    s += fabsf(v.x) + fabsf(v.y) + fabsf(v.z) + fabsf(v.w);
  }
  #pragma unroll
  for (int off = 32; off > 0; off >>= 1) s += __shfl_down(s, off);
  __shared__ float sm[4];
  if ((threadIdx.x & 63) == 0) sm[threadIdx.x >> 6] = s;
  __syncthreads();
  if (threadIdx.x == 0) part[blockIdx.x] = sm[0] + sm[1] + sm[2] + sm[3];
}

// ---------------- K2: finalize scale = mean(|w|) ----------------------------
__global__ void k_abs_final(const float* __restrict__ part, float* __restrict__ scal) {
  float s = part[threadIdx.x];           // exactly 256 partials, block = 256
  #pragma unroll
  for (int off = 32; off > 0; off >>= 1) s += __shfl_down(s, off);
  __shared__ float sm[4];
  if ((threadIdx.x & 63) == 0) sm[threadIdx.x >> 6] = s;
  __syncthreads();
  if (threadIdx.x == 0) scal[0] = (sm[0] + sm[1] + sm[2] + sm[3]) / (float)WELEMS;
}

__device__ __forceinline__ int quant4(float4 v, float sc) {
  int a = (int)rintf(v.x / sc); a = a < -128 ? -128 : (a > 127 ? 127 : a);
  int b = (int)rintf(v.y / sc); b = b < -128 ? -128 : (b > 127 ? 127 : b);
  int c = (int)rintf(v.z / sc); c = c < -128 ? -128 : (c > 127 ? 127 : c);
  int d = (int)rintf(v.w / sc); d = d < -128 ? -128 : (d > 127 ? 127 : d);
  return (a & 255) | ((b & 255) << 8) | ((c & 255) << 16) | ((d & 255) << 24);
}

__device__ __forceinline__ int tern4(float4 v, float s) {
  int a = (int)rintf(v.x / s); a = a < -1 ? -1 : (a > 1 ? 1 : a);
  int b = (int)rintf(v.y / s); b = b < -1 ? -1 : (b > 1 ? 1 : b);
  int c = (int)rintf(v.z / s); c = c < -1 ? -1 : (c > 1 ? 1 : c);
  int d = (int)rintf(v.w / s); d = d < -1 ? -1 : (d > 1 ? 1 : d);
  return (a & 255) | ((b & 255) << 8) | ((c & 255) << 16) | ((d & 255) << 24);
}

// LDS row stride for the transpose buffers: 2052 B (513 dwords, odd ->
// bank = (l*513 + k)%32 spreads 32 rows over all 32 banks; <=2-way = free).
static constexpr int LSTR = 2052;

// ---------------- K3: ternary weight quantize + fragment-major pack ---------
__global__ __launch_bounds__(512) void k_wquant(const float* __restrict__ w,
                                                char* __restrict__ wq,
                                                const float* __restrict__ scal) {
  __shared__ char sq[32 * LSTR];
  const float s  = scal[0] + 1e-8f;
  const int   Rg = blockIdx.x;
  const int   wv = threadIdx.x >> 6;     // 0..7
  const int   l  = threadIdx.x & 63;

  #pragma unroll
  for (int it = 0; it < 4; ++it) {
    const int rs = it * 8 + wv;          // row slot 0..31
    const float4* wr = (const float4*)(w + (size_t)(Rg * 32 + rs) * Kdim);
    #pragma unroll
    for (int c = 0; c < 8; ++c)
      *(int*)(&sq[rs * LSTR + (c * 64 + l) * 4]) = tern4(wr[c * 64 + l], s);
  }
  __syncthreads();
  char* dst = wq + (size_t)Rg * 65536;
  #pragma unroll
  for (int i = 0; i < 8; ++i) {
    const int c = i * 8 + wv;            // chunk 0..63
    int p[4];
    #pragma unroll
    for (int j = 0; j < 4; ++j)
      p[j] = *(const int*)(&sq[(l & 31) * LSTR + c * 32 + (l >> 5) * 16 + j * 4]);
    *(int4*)(dst + c * 1024 + l * 16) = make_int4(p[0], p[1], p[2], p[3]);
  }
}

// ---------------- K4: per-row absmax + int8 quantize + pack -----------------
__global__ __launch_bounds__(512) void k_xquant(const float* __restrict__ x,
                                                char* __restrict__ xq,
                                                float* __restrict__ xs) {
  __shared__ char sq[32 * LSTR];
  const int Rg = blockIdx.x;
  const int wv = threadIdx.x >> 6;       // 0..7
  const int l  = threadIdx.x & 63;

  #pragma unroll
  for (int it = 0; it < 4; ++it) {
    const int rs  = it * 8 + wv;
    const int row = Rg * 32 + rs;
    const float4* xr = (const float4*)(x + (size_t)row * Kdim);
    float4 v[8];
    float  m = 0.f;
    #pragma unroll
    for (int c = 0; c < 8; ++c) {
      v[c] = xr[c * 64 + l];
      m = fmaxf(m, fmaxf(fmaxf(fabsf(v[c].x), fabsf(v[c].y)),
                         fmaxf(fabsf(v[c].z), fabsf(v[c].w))));
    }
    #pragma unroll
    for (int off = 1; off < 64; off <<= 1) m = fmaxf(m, __shfl_xor(m, off));
    m = fmaxf(m, 1e-8f);
    const float sc = m / 127.0f;
    if (l == 0) xs[row] = sc;
    #pragma unroll
    for (int c = 0; c < 8; ++c)
      *(int*)(&sq[rs * LSTR + (c * 64 + l) * 4]) = quant4(v[c], sc);
  }
  __syncthreads();
  char* dst = xq + (size_t)Rg * 65536;
  #pragma unroll
  for (int i = 0; i < 8; ++i) {
    const int c = i * 8 + wv;
    int p[4];
    #pragma unroll
    for (int j = 0; j < 4; ++j)
      p[j] = *(const int*)(&sq[(l & 31) * LSTR + c * 32 + (l >> 5) * 16 + j * 4]);
    *(int4*)(dst + c * 1024 + l * 16) = make_int4(p[0], p[1], p[2], p[3]);
  }
}

// ---------------- K5: int8 MFMA GEMM, 128x128, HIGH TLP + B-direct ----------
// out = (scale*xs[m]) * (xq . wq^T) + bias
// 256 threads = 4 waves (2x2), wave tile 64x64 = acc[2][2] of 32x32 mfma.
// R17's high-TLP regime (4 blocks/CU, 16 waves) kept; B now loads DIRECT
// global->reg (wq 4 MB = L2-resident; per-lane frag = contiguous 16 B of a
// packed chunk; wr-paired waves load identical addresses -> L1 hit).
// Removes B's DMA-write + ds_read: LDS traffic/epoch halves (192->96 KB).
// LDS = ring-2 x 8 KiB (A only).
// Per tile: {bar; aF ds_read x4; lgkmcnt(0); bar; BLOAD(t) x4; STAGE_A(t+2)
// x2; vmcnt(2) -> bF landed, stage (newest 2) stays in flight; setprio MFMA}.
// Per-wave A(t) provably lands before barrier t (prior iter's vmcnt(2)).
__global__ __launch_bounds__(256, 4) void k_gemm(
    const char* __restrict__ xq, const char* __restrict__ wq,
    const float* __restrict__ xs, const float* __restrict__ scal,
    const float* __restrict__ bias, float* __restrict__ out) {
  __shared__ __attribute__((aligned(128))) char lds[2][8192];

  // XCD-aware bijective swizzle: 2048 blocks, 2048 % 8 == 0.
  const int hw  = blockIdx.x;
  const int lin = (hw & 7) * 256 + (hw >> 3);
  const int bm  = lin >> 4;               // 128 M-tiles
  const int bn  = lin & 15;               // 16 N-tiles

  const int tid = threadIdx.x;
  const int w   = tid >> 6;               // wave 0..3
  const int l   = tid & 63;
  const int wr  = w >> 1, wc = w & 1;     // 2 x 2 wave grid
  const int l16 = l * 16;

  // A staging: wave w stages R-group w (rows w*32..w*32+31)
  const char* gA  = xq + (size_t)(bm * 4 + w) * 65536 + l16;
  // B direct: wave (wc) reads R-groups {bn*4 + wc*2 + ni}
  const char* gBf = wq + (size_t)(bn * 4 + wc * 2) * 65536 + l16;
  const int   w2k = w * 2048;

#define STAGE_A(t_)                                                       \
  { char* sb = &lds[(t_) & 1][0]; const int kb_ = (t_) * 2048;            \
    gload_lds16(gA + kb_,        sb + w2k);                               \
    gload_lds16(gA + kb_ + 1024, sb + w2k + 1024); }

#define BLOAD(DST, t_)                                                    \
  _Pragma("unroll") for (int ni = 0; ni < 2; ++ni)                        \
    _Pragma("unroll") for (int ks = 0; ks < 2; ++ks)                      \
      DST[ni][ks] = *(const i32x4*)(gBf + (size_t)ni * 65536 + ((t_) * 2 + ks) * 1024);

  i32x16 acc[2][2] = {};

  STAGE_A(0); STAGE_A(1);                 // 4 per-wave A-gloads in flight
  asm volatile("s_waitcnt vmcnt(2)" ::: "memory");   // A(0) landed

#define TILE(T_, DOSTG, VMMID)                                              \
  {                                                                         \
    __builtin_amdgcn_s_barrier();                                           \
    asm volatile("" ::: "memory");                                          \
    const char* base_ = &lds[(T_) & 1][0];                                  \
    i32x4 aF[2][2], bF[2][2];                                               \
    _Pragma("unroll") for (int mi = 0; mi < 2; ++mi)                        \
      _Pragma("unroll") for (int ks = 0; ks < 2; ++ks)                      \
        aF[mi][ks] = *(const i32x4*)(base_ + ((wr*2+mi)*2+ks)*1024 + l16);  \
    asm volatile("s_waitcnt lgkmcnt(0)" ::: "memory");                      \
    __builtin_amdgcn_sched_barrier(0);                                      \
    __builtin_amdgcn_s_barrier();                                           \
    asm volatile("" ::: "memory");                                          \
    BLOAD(bF, T_)                                                           \
    if (DOSTG) STAGE_A((T_) + 2)                                            \
    VMMID                                                                   \
    __builtin_amdgcn_s_setprio(1);                                          \
    _Pragma("unroll") for (int ks = 0; ks < 2; ++ks)                        \
      _Pragma("unroll") for (int mi = 0; mi < 2; ++mi)                      \
        _Pragma("unroll") for (int ni = 0; ni < 2; ++ni)                    \
          acc[mi][ni] = __builtin_amdgcn_mfma_i32_32x32x32_i8(              \
              aF[mi][ks], bF[ni][ks], acc[mi][ni], 0, 0, 0);                \
    __builtin_amdgcn_s_setprio(0);                                          \
  }

#define VM2  asm volatile("s_waitcnt vmcnt(2)" ::: "memory");
#define VM0  asm volatile("s_waitcnt vmcnt(0)" ::: "memory");

  #pragma unroll 2
  for (int t = 0; t < 30; ++t)            // uniform: BLOAD(t), stage t+2
    TILE(t, 1, VM2)
  TILE(30, 0, VM2)                        // A(31) already confirmed landed
  TILE(31, 0, VM0)                        // queue empties (last tile only)
#undef TILE
#undef STAGE_A
#undef BLOAD
#undef VM2
#undef VM0

  // epilogue: C/D mapping col = lane&31, row = (r&3) + 8*(r>>2) + 4*(lane>>5)
  const float wsc = scal[0];
  const int   lhi = (l >> 5) * 4, lcol = l & 31;
  float bc[2];
  #pragma unroll
  for (int ni = 0; ni < 2; ++ni)
    bc[ni] = bias[bn * 128 + wc * 64 + ni * 32 + lcol];

  #pragma unroll
  for (int mi = 0; mi < 2; ++mi) {
    const int rb = bm * 128 + wr * 64 + mi * 32 + lhi;
    #pragma unroll
    for (int r = 0; r < 16; ++r) {
      const int   row = rb + (r & 3) + 8 * (r >> 2);
      const float sv  = wsc * xs[row];
      #pragma unroll
      for (int ni = 0; ni < 2; ++ni) {
        const int col = bn * 128 + wc * 64 + ni * 32 + lcol;
        out[(size_t)row * Ndim + col] = (float)acc[mi][ni][r] * sv + bc[ni];
      }
    }
  }
}

// ---------------- launch -----------------------------------------------------
extern "C" void kernel_launch(void* const* d_in, const int* in_sizes, int n_in,
                              void* d_out, int out_size, void* d_ws, size_t ws_size,
                              hipStream_t stream) {
  const float* x    = (const float*)d_in[0];
  const float* wgt  = (const float*)d_in[1];
  const float* bias = (const float*)d_in[2];
  float* out = (float*)d_out;

  float* ws_f = (float*)d_ws;
  float* scal = ws_f;               // 1 float
  float* part = ws_f + 64;          // 256 floats
  float* xs   = ws_f + 1024;        // 16384 floats
  char*  wq   = (char*)(ws_f + 20480);          // 4 MiB packed, 16B-aligned
  char*  xq   = wq + (size_t)WELEMS;            // 32 MiB packed, 16B-aligned

  hipLaunchKernelGGL(k_abs_part,  dim3(256),      dim3(256), 0, stream, wgt, part);
  hipLaunchKernelGGL(k_abs_final, dim3(1),        dim3(256), 0, stream, part, scal);
  hipLaunchKernelGGL(k_wquant,    dim3(64),       dim3(512), 0, stream, wgt, wq, scal);
  hipLaunchKernelGGL(k_xquant,    dim3(Mdim/32),  dim3(512), 0, stream, x, xq, xs);
  hipLaunchKernelGGL(k_gemm,      dim3((Mdim/128)*(Ndim/128)), dim3(256), 0, stream,
                     xq, wq, xs, scal, bias, out);
}

// Round 20
// 138.892 us; speedup vs baseline: 1.1460x; 1.0567x over previous
//
#include <hip/hip_runtime.h>
#include <stdint.h>

typedef int i32x4  __attribute__((ext_vector_type(4)));
typedef int i32x16 __attribute__((ext_vector_type(16)));

static constexpr int Mdim   = 16384;     // B*S = 8*2048
static constexpr int Kdim   = 2048;      // D_IN
static constexpr int Ndim   = 2048;      // D_OUT
static constexpr int WELEMS = Ndim * Kdim;   // 4194304

// Fragment-major pack layout (shared by packers and GEMM):
//   chunk(R, c) = 1024 B at base + (R*64 + c)*1024
//   byte l*16 + b of a chunk holds row R*32 + (l&31), k = c*32 + (l>>5)*16 + b

// ---------------- async global->LDS (16B per lane, lane-ordered dest) -------
__device__ __forceinline__ void gload_lds16(const void* g, void* l) {
  __builtin_amdgcn_global_load_lds(
      (const __attribute__((address_space(1))) void*)g,
      (__attribute__((address_space(3))) void*)l,
      16, 0, 0);
}

// ---------------- K1: partial sums of |w| -----------------------------------
__global__ void k_abs_part(const float* __restrict__ w, float* __restrict__ part) {
  const float4* w4 = (const float4*)w;
  float s = 0.f;
  int idx = blockIdx.x * 256 + threadIdx.x;
  #pragma unroll 4
  for (int i = idx; i < WELEMS / 4; i += 256 * 256) {
    float4 v = w4[i];
    s += fabsf(v.x) + fabsf(v.y) + fabsf(v.z) + fabsf(v.w);
  }
  #pragma unroll
  for (int off = 32; off > 0; off >>= 1) s += __shfl_down(s, off);
  __shared__ float sm[4];
  if ((threadIdx.x & 63) == 0) sm[threadIdx.x >> 6] = s;
  __syncthreads();
  if (threadIdx.x == 0) part[blockIdx.x] = sm[0] + sm[1] + sm[2] + sm[3];
}

__device__ __forceinline__ int quant4(float4 v, float sc) {
  int a = (int)rintf(v.x / sc); a = a < -128 ? -128 : (a > 127 ? 127 : a);
  int b = (int)rintf(v.y / sc); b = b < -128 ? -128 : (b > 127 ? 127 : b);
  int c = (int)rintf(v.z / sc); c = c < -128 ? -128 : (c > 127 ? 127 : c);
  int d = (int)rintf(v.w / sc); d = d < -128 ? -128 : (d > 127 ? 127 : d);
  return (a & 255) | ((b & 255) << 8) | ((c & 255) << 16) | ((d & 255) << 24);
}

__device__ __forceinline__ int tern4(float4 v, float s) {
  int a = (int)rintf(v.x / s); a = a < -1 ? -1 : (a > 1 ? 1 : a);
  int b = (int)rintf(v.y / s); b = b < -1 ? -1 : (b > 1 ? 1 : b);
  int c = (int)rintf(v.z / s); c = c < -1 ? -1 : (c > 1 ? 1 : c);
  int d = (int)rintf(v.w / s); d = d < -1 ? -1 : (d > 1 ? 1 : d);
  return (a & 255) | ((b & 255) << 8) | ((c & 255) << 16) | ((d & 255) << 24);
}

// LDS row stride for the transpose buffers: 2052 B (513 dwords, odd ->
// bank = (l*513 + k)%32 spreads 32 rows over all 32 banks; <=2-way = free).
static constexpr int LSTR = 2052;

// ---------------- K3: ternary weight quantize + pack (inlines the scale) ----
// grid 64 x 512 thr.  First reduces part[256] in-block (replaces k_abs_final).
__global__ __launch_bounds__(512) void k_wquant(const float* __restrict__ w,
                                                char* __restrict__ wq,
                                                const float* __restrict__ part) {
  __shared__ char sq[32 * LSTR];
  __shared__ float smr[8];
  const int wv = threadIdx.x >> 6;       // 0..7
  const int l  = threadIdx.x & 63;

  // ---- inline scale = mean(|w|): reduce part[0..255] ----
  float ps = (threadIdx.x < 256) ? part[threadIdx.x] : 0.f;
  #pragma unroll
  for (int off = 32; off > 0; off >>= 1) ps += __shfl_down(ps, off);
  if (l == 0) smr[wv] = ps;
  __syncthreads();
  const float s = (smr[0] + smr[1] + smr[2] + smr[3] +
                   smr[4] + smr[5] + smr[6] + smr[7]) / (float)WELEMS + 1e-8f;

  const int Rg = blockIdx.x;
  #pragma unroll
  for (int it = 0; it < 4; ++it) {
    const int rs = it * 8 + wv;          // row slot 0..31
    const float4* wr = (const float4*)(w + (size_t)(Rg * 32 + rs) * Kdim);
    #pragma unroll
    for (int c = 0; c < 8; ++c)
      *(int*)(&sq[rs * LSTR + (c * 64 + l) * 4]) = tern4(wr[c * 64 + l], s);
  }
  __syncthreads();
  char* dst = wq + (size_t)Rg * 65536;
  #pragma unroll
  for (int i = 0; i < 8; ++i) {
    const int c = i * 8 + wv;            // chunk 0..63
    int p[4];
    #pragma unroll
    for (int j = 0; j < 4; ++j)
      p[j] = *(const int*)(&sq[(l & 31) * LSTR + c * 32 + (l >> 5) * 16 + j * 4]);
    *(int4*)(dst + c * 1024 + l * 16) = make_int4(p[0], p[1], p[2], p[3]);
  }
}

// ---------------- K4: per-row absmax + int8 quantize + pack -----------------
__global__ __launch_bounds__(512) void k_xquant(const float* __restrict__ x,
                                                char* __restrict__ xq,
                                                float* __restrict__ xs) {
  __shared__ char sq[32 * LSTR];
  const int Rg = blockIdx.x;
  const int wv = threadIdx.x >> 6;       // 0..7
  const int l  = threadIdx.x & 63;

  #pragma unroll
  for (int it = 0; it < 4; ++it) {
    const int rs  = it * 8 + wv;
    const int row = Rg * 32 + rs;
    const float4* xr = (const float4*)(x + (size_t)row * Kdim);
    float4 v[8];
    float  m = 0.f;
    #pragma unroll
    for (int c = 0; c < 8; ++c) {
      v[c] = xr[c * 64 + l];
      m = fmaxf(m, fmaxf(fmaxf(fabsf(v[c].x), fabsf(v[c].y)),
                         fmaxf(fabsf(v[c].z), fabsf(v[c].w))));
    }
    #pragma unroll
    for (int off = 1; off < 64; off <<= 1) m = fmaxf(m, __shfl_xor(m, off));
    m = fmaxf(m, 1e-8f);
    const float sc = m / 127.0f;
    if (l == 0) xs[row] = sc;
    #pragma unroll
    for (int c = 0; c < 8; ++c)
      *(int*)(&sq[rs * LSTR + (c * 64 + l) * 4]) = quant4(v[c], sc);
  }
  __syncthreads();
  char* dst = xq + (size_t)Rg * 65536;
  #pragma unroll
  for (int i = 0; i < 8; ++i) {
    const int c = i * 8 + wv;
    int p[4];
    #pragma unroll
    for (int j = 0; j < 4; ++j)
      p[j] = *(const int*)(&sq[(l & 31) * LSTR + c * 32 + (l >> 5) * 16 + j * 4]);
    *(int4*)(dst + c * 1024 + l * 16) = make_int4(p[0], p[1], p[2], p[3]);
  }
}

// ---------------- K5: int8 MFMA GEMM, 128x128, RING-3, 1 barrier/tile -------
// out = (scale*xs[m]) * (xq . wq^T) + bias
// 256 threads = 4 waves (2x2), wave tile 64x64 = acc[2][2] (64 AGPR; total
// regs ~124 <= 128 -> up to 4 waves/SIMD budget; LDS 48 KiB -> 3 blocks/CU).
// RING-3 eliminates barrier #2: STAGE(t+2) targets buf[(t+2)%3], which was
// last read at tile t-1 -- every wave passed barrier t only after finishing
// its t-1 reads (MFMA consumed them), so the DMA overwrite is race-free.
// Per tile: {vmcnt(4); s_barrier; STAGE(t+2); ds_read 8 x b128; setprio MFMA}
// -- HALF the sync events of R17.  vmcnt(4) leaves t+1's 4 loads in flight;
// never 0 until the peeled last tile.  Loop unrolled x3 for static buf idx.
__global__ __launch_bounds__(256, 4) void k_gemm(
    const char* __restrict__ xq, const char* __restrict__ wq,
    const float* __restrict__ xs, const float* __restrict__ scal_part,
    const float* __restrict__ bias, float* __restrict__ out) {
  __shared__ __attribute__((aligned(128))) char lds[3][16384];

  // XCD-aware bijective swizzle: 2048 blocks, 2048 % 8 == 0.
  const int hw  = blockIdx.x;
  const int lin = (hw & 7) * 256 + (hw >> 3);
  const int bm  = lin >> 4;               // 128 M-tiles
  const int bn  = lin & 15;               // 16 N-tiles

  const int tid = threadIdx.x;
  const int w   = tid >> 6;               // wave 0..3
  const int l   = tid & 63;
  const int wr  = w >> 1, wc = w & 1;     // 2 x 2 wave grid
  const int l16 = l * 16;

  // scale = mean(|w|): cheap in-wave reduce of part[256] (4 vals/lane)
  float ps = scal_part[l] + scal_part[l + 64] + scal_part[l + 128] + scal_part[l + 192];
  #pragma unroll
  for (int off = 32; off > 0; off >>= 1) ps += __shfl_down(ps, off);
  const float wsc = __shfl(ps, 0) / (float)WELEMS;   // pre-clip scale (ref scales by this)

  const char* gA = xq + (size_t)(bm * 4 + w) * 65536 + l16;
  const char* gB = wq + (size_t)(bn * 4 + w) * 65536 + l16;
  const int   w2k = w * 2048;

#define STAGE(t_, buf_)                                                   \
  { char* sb = &lds[buf_][0]; const int kb_ = (t_) * 2048;                \
    gload_lds16(gA + kb_,        sb + w2k);                               \
    gload_lds16(gA + kb_ + 1024, sb + w2k + 1024);                        \
    gload_lds16(gB + kb_,        sb + 8192 + w2k);                        \
    gload_lds16(gB + kb_ + 1024, sb + 8192 + w2k + 1024); }

  i32x16 acc[2][2] = {};

  STAGE(0, 0); STAGE(1, 1);               // 8 per-wave loads in flight

#define TILE(T_, RB_, SB_, VMTOK, DOSTG)                                    \
  {                                                                         \
    VMTOK                                                                   \
    __builtin_amdgcn_s_barrier();                                           \
    asm volatile("" ::: "memory");                                          \
    if (DOSTG) STAGE((T_) + 2, SB_)                                         \
    const char* base_ = &lds[RB_][0];                                       \
    i32x4 aF[2][2], bF[2][2];                                               \
    _Pragma("unroll") for (int mi = 0; mi < 2; ++mi)                        \
      _Pragma("unroll") for (int ks = 0; ks < 2; ++ks)                      \
        aF[mi][ks] = *(const i32x4*)(base_ + ((wr*2+mi)*2+ks)*1024 + l16);  \
    _Pragma("unroll") for (int ni = 0; ni < 2; ++ni)                        \
      _Pragma("unroll") for (int ks = 0; ks < 2; ++ks)                      \
        bF[ni][ks] = *(const i32x4*)(base_ + 8192 + ((wc*2+ni)*2+ks)*1024 + l16); \
    __builtin_amdgcn_s_setprio(1);                                          \
    _Pragma("unroll") for (int ks = 0; ks < 2; ++ks)                        \
      _Pragma("unroll") for (int mi = 0; mi < 2; ++mi)                      \
        _Pragma("unroll") for (int ni = 0; ni < 2; ++ni)                    \
          acc[mi][ni] = __builtin_amdgcn_mfma_i32_32x32x32_i8(              \
              aF[mi][ks], bF[ni][ks], acc[mi][ni], 0, 0, 0);                \
    __builtin_amdgcn_s_setprio(0);                                          \
  }

#define VM4  asm volatile("s_waitcnt vmcnt(4)" ::: "memory");
#define VM0  asm volatile("s_waitcnt vmcnt(0)" ::: "memory");

  for (int t = 0; t < 30; t += 3) {       // tiles 0..29, static ring-3 idx
    TILE(t,     0, 2, VM4, 1);            // read buf0, stage t+2 -> buf2
    TILE(t + 1, 1, 0, VM4, 1);            // read buf1, stage t+3 -> buf0
    TILE(t + 2, 2, 1, VM4, 1);            // read buf2, stage t+4 -> buf1
  }
  TILE(30, 0, 0, VM4, 0);                 // tile 31's loads stay in flight
  TILE(31, 1, 0, VM0, 0);                 // queue empties (last tile only)
#undef TILE
#undef STAGE
#undef VM4
#undef VM0

  // epilogue: C/D mapping col = lane&31, row = (r&3) + 8*(r>>2) + 4*(lane>>5)
  const int lhi = (l >> 5) * 4, lcol = l & 31;
  float bc[2];
  #pragma unroll
  for (int ni = 0; ni < 2; ++ni)
    bc[ni] = bias[bn * 128 + wc * 64 + ni * 32 + lcol];

  #pragma unroll
  for (int mi = 0; mi < 2; ++mi) {
    const int rb = bm * 128 + wr * 64 + mi * 32 + lhi;
    #pragma unroll
    for (int r = 0; r < 16; ++r) {
      const int   row = rb + (r & 3) + 8 * (r >> 2);
      const float sv  = wsc * xs[row];
      #pragma unroll
      for (int ni = 0; ni < 2; ++ni) {
        const int col = bn * 128 + wc * 64 + ni * 32 + lcol;
        out[(size_t)row * Ndim + col] = (float)acc[mi][ni][r] * sv + bc[ni];
      }
    }
  }
}

// ---------------- launch -----------------------------------------------------
extern "C" void kernel_launch(void* const* d_in, const int* in_sizes, int n_in,
                              void* d_out, int out_size, void* d_ws, size_t ws_size,
                              hipStream_t stream) {
  const float* x    = (const float*)d_in[0];
  const float* wgt  = (const float*)d_in[1];
  const float* bias = (const float*)d_in[2];
  float* out = (float*)d_out;

  float* ws_f = (float*)d_ws;
  float* part = ws_f + 64;          // 256 floats
  float* xs   = ws_f + 1024;        // 16384 floats
  char*  wq   = (char*)(ws_f + 20480);          // 4 MiB packed, 16B-aligned
  char*  xq   = wq + (size_t)WELEMS;            // 32 MiB packed, 16B-aligned

  hipLaunchKernelGGL(k_abs_part,  dim3(256),      dim3(256), 0, stream, wgt, part);
  hipLaunchKernelGGL(k_wquant,    dim3(64),       dim3(512), 0, stream, wgt, wq, part);
  hipLaunchKernelGGL(k_xquant,    dim3(Mdim/32),  dim3(512), 0, stream, x, xq, xs);
  hipLaunchKernelGGL(k_gemm,      dim3((Mdim/128)*(Ndim/128)), dim3(256), 0, stream,
                     xq, wq, xs, part, bias, out);
}

// Round 21
// 133.737 us; speedup vs baseline: 1.1902x; 1.0386x over previous
//
#include <hip/hip_runtime.h>
#include <stdint.h>

typedef int i32x4  __attribute__((ext_vector_type(4)));
typedef int i32x16 __attribute__((ext_vector_type(16)));

static constexpr int Mdim   = 16384;     // B*S = 8*2048
static constexpr int Kdim   = 2048;      // D_IN
static constexpr int Ndim   = 2048;      // D_OUT
static constexpr int WELEMS = Ndim * Kdim;   // 4194304

// Fragment-major pack layout (shared by packers and GEMM):
//   chunk(R, c) = 1024 B at base + (R*64 + c)*1024
//   byte l*16 + b of a chunk holds row R*32 + (l&31), k = c*32 + (l>>5)*16 + b

// ---------------- async global->LDS (16B per lane, lane-ordered dest) -------
__device__ __forceinline__ void gload_lds16(const void* g, void* l) {
  __builtin_amdgcn_global_load_lds(
      (const __attribute__((address_space(1))) void*)g,
      (__attribute__((address_space(3))) void*)l,
      16, 0, 0);
}

// ---------------- K1: partial sums of |w| -----------------------------------
__global__ void k_abs_part(const float* __restrict__ w, float* __restrict__ part) {
  const float4* w4 = (const float4*)w;
  float s = 0.f;
  int idx = blockIdx.x * 256 + threadIdx.x;
  #pragma unroll 4
  for (int i = idx; i < WELEMS / 4; i += 256 * 256) {
    float4 v = w4[i];
    s += fabsf(v.x) + fabsf(v.y) + fabsf(v.z) + fabsf(v.w);
  }
  #pragma unroll
  for (int off = 32; off > 0; off >>= 1) s += __shfl_down(s, off);
  __shared__ float sm[4];
  if ((threadIdx.x & 63) == 0) sm[threadIdx.x >> 6] = s;
  __syncthreads();
  if (threadIdx.x == 0) part[blockIdx.x] = sm[0] + sm[1] + sm[2] + sm[3];
}

__device__ __forceinline__ int quant4(float4 v, float sc) {
  int a = (int)rintf(v.x / sc); a = a < -128 ? -128 : (a > 127 ? 127 : a);
  int b = (int)rintf(v.y / sc); b = b < -128 ? -128 : (b > 127 ? 127 : b);
  int c = (int)rintf(v.z / sc); c = c < -128 ? -128 : (c > 127 ? 127 : c);
  int d = (int)rintf(v.w / sc); d = d < -128 ? -128 : (d > 127 ? 127 : d);
  return (a & 255) | ((b & 255) << 8) | ((c & 255) << 16) | ((d & 255) << 24);
}

__device__ __forceinline__ int tern4(float4 v, float s) {
  int a = (int)rintf(v.x / s); a = a < -1 ? -1 : (a > 1 ? 1 : a);
  int b = (int)rintf(v.y / s); b = b < -1 ? -1 : (b > 1 ? 1 : b);
  int c = (int)rintf(v.z / s); c = c < -1 ? -1 : (c > 1 ? 1 : c);
  int d = (int)rintf(v.w / s); d = d < -1 ? -1 : (d > 1 ? 1 : d);
  return (a & 255) | ((b & 255) << 8) | ((c & 255) << 16) | ((d & 255) << 24);
}

// LDS row stride for the transpose buffers: 2052 B (513 dwords, odd ->
// bank = (l*513 + k)%32 spreads 32 rows over all 32 banks; <=2-way = free).
static constexpr int LSTR = 2052;

// ---------------- K3: ternary weight quantize + pack (inlines the scale) ----
__global__ __launch_bounds__(512) void k_wquant(const float* __restrict__ w,
                                                char* __restrict__ wq,
                                                const float* __restrict__ part) {
  __shared__ char sq[32 * LSTR];
  __shared__ float smr[8];
  const int wv = threadIdx.x >> 6;       // 0..7
  const int l  = threadIdx.x & 63;

  // ---- inline scale = mean(|w|): reduce part[0..255] ----
  float ps = (threadIdx.x < 256) ? part[threadIdx.x] : 0.f;
  #pragma unroll
  for (int off = 32; off > 0; off >>= 1) ps += __shfl_down(ps, off);
  if (l == 0) smr[wv] = ps;
  __syncthreads();
  const float s = (smr[0] + smr[1] + smr[2] + smr[3] +
                   smr[4] + smr[5] + smr[6] + smr[7]) / (float)WELEMS + 1e-8f;

  const int Rg = blockIdx.x;
  #pragma unroll
  for (int it = 0; it < 4; ++it) {
    const int rs = it * 8 + wv;          // row slot 0..31
    const float4* wr = (const float4*)(w + (size_t)(Rg * 32 + rs) * Kdim);
    #pragma unroll
    for (int c = 0; c < 8; ++c)
      *(int*)(&sq[rs * LSTR + (c * 64 + l) * 4]) = tern4(wr[c * 64 + l], s);
  }
  __syncthreads();
  char* dst = wq + (size_t)Rg * 65536;
  #pragma unroll
  for (int i = 0; i < 8; ++i) {
    const int c = i * 8 + wv;            // chunk 0..63
    int p[4];
    #pragma unroll
    for (int j = 0; j < 4; ++j)
      p[j] = *(const int*)(&sq[(l & 31) * LSTR + c * 32 + (l >> 5) * 16 + j * 4]);
    *(int4*)(dst + c * 1024 + l * 16) = make_int4(p[0], p[1], p[2], p[3]);
  }
}

// ---------------- K4: per-row absmax + int8 quantize + pack -----------------
__global__ __launch_bounds__(512) void k_xquant(const float* __restrict__ x,
                                                char* __restrict__ xq,
                                                float* __restrict__ xs) {
  __shared__ char sq[32 * LSTR];
  const int Rg = blockIdx.x;
  const int wv = threadIdx.x >> 6;       // 0..7
  const int l  = threadIdx.x & 63;

  #pragma unroll
  for (int it = 0; it < 4; ++it) {
    const int rs  = it * 8 + wv;
    const int row = Rg * 32 + rs;
    const float4* xr = (const float4*)(x + (size_t)row * Kdim);
    float4 v[8];
    float  m = 0.f;
    #pragma unroll
    for (int c = 0; c < 8; ++c) {
      v[c] = xr[c * 64 + l];
      m = fmaxf(m, fmaxf(fmaxf(fabsf(v[c].x), fabsf(v[c].y)),
                         fmaxf(fabsf(v[c].z), fabsf(v[c].w))));
    }
    #pragma unroll
    for (int off = 1; off < 64; off <<= 1) m = fmaxf(m, __shfl_xor(m, off));
    m = fmaxf(m, 1e-8f);
    const float sc = m / 127.0f;
    if (l == 0) xs[row] = sc;
    #pragma unroll
    for (int c = 0; c < 8; ++c)
      *(int*)(&sq[rs * LSTR + (c * 64 + l) * 4]) = quant4(v[c], sc);
  }
  __syncthreads();
  char* dst = xq + (size_t)Rg * 65536;
  #pragma unroll
  for (int i = 0; i < 8; ++i) {
    const int c = i * 8 + wv;
    int p[4];
    #pragma unroll
    for (int j = 0; j < 4; ++j)
      p[j] = *(const int*)(&sq[(l & 31) * LSTR + c * 32 + (l >> 5) * 16 + j * 4]);
    *(int4*)(dst + c * 1024 + l * 16) = make_int4(p[0], p[1], p[2], p[3]);
  }
}

// ---------------- K5: int8 MFMA GEMM, 256x128 tile, RING-3, 16 waves/CU -----
// out = (scale*xs[m]) * (xq . wq^T) + bias
// 512 threads = 8 waves (4M x 2N), wave tile 64x64 = acc[2][2] (64 AGPR,
// total regs <= 128 -> 4 waves/SIMD; launch_bounds(512,4) -> 2 blocks/CU =
// 16 waves, R17's proven TLP).  Tile asymmetry halves DMA per MFMA
// (24 KB stages 64 MFMA vs R17's 32 KB per 64).  RING-3 (3 x 24 KiB = 72 KiB)
// gives ONE barrier/tile (R20's proven-safe pattern: STAGE(t+2) targets
// buf[(t-1)%3], drained by barrier t).  Staging = 24 chunks/tile = exactly
// 3 gloads/wave (wave-uniform map q = w*3+j); vmcnt(3) confirms tile t while
// t+1's 3 stay in flight; never 0 until the peeled last tile.
__global__ __launch_bounds__(512, 4) void k_gemm(
    const char* __restrict__ xq, const char* __restrict__ wq,
    const float* __restrict__ xs, const float* __restrict__ scal_part,
    const float* __restrict__ bias, float* __restrict__ out) {
  __shared__ __attribute__((aligned(128))) char lds[3][24576];

  // XCD-aware bijective swizzle: 1024 blocks, 1024 % 8 == 0.
  const int hw  = blockIdx.x;
  const int lin = (hw & 7) * 128 + (hw >> 3);
  const int bm  = lin >> 4;               // 64 M-tiles (256 rows)
  const int bn  = lin & 15;               // 16 N-tiles (128 cols)

  const int tid = threadIdx.x;
  const int w   = tid >> 6;               // wave 0..7
  const int l   = tid & 63;
  const int wr  = w >> 1, wc = w & 1;     // 4 x 2 wave grid
  const int l16 = l * 16;

  // scale = mean(|w|): in-wave reduce of part[256] (4 vals/lane)
  float ps = scal_part[l] + scal_part[l + 64] + scal_part[l + 128] + scal_part[l + 192];
  #pragma unroll
  for (int off = 32; off > 0; off >>= 1) ps += __shfl_down(ps, off);
  const float wsc = __shfl(ps, 0) / (float)WELEMS;

  // staging map: q = w*3+j over 24 chunks = [A: rg 0..7 x ks 0,1][B: rg 0..3 x ks 0,1]
  const char* gsrc[3];
  int         loff[3];
  #pragma unroll
  for (int j = 0; j < 3; ++j) {
    const int q = w * 3 + j;             // wave-uniform
    if (q < 16) {
      const int rg = q >> 1, ks = q & 1;
      gsrc[j] = xq + (size_t)(bm * 8 + rg) * 65536 + ks * 1024 + l16;
      loff[j] = rg * 2048 + ks * 1024;
    } else {
      const int p = q - 16, rg = p >> 1, ks = p & 1;
      gsrc[j] = wq + (size_t)(bn * 4 + rg) * 65536 + ks * 1024 + l16;
      loff[j] = 16384 + rg * 2048 + ks * 1024;
    }
  }

#define STAGE(t_, buf_)                                                   \
  { const size_t kb_ = (size_t)(t_) * 2048;                               \
    gload_lds16(gsrc[0] + kb_, &lds[buf_][loff[0]]);                      \
    gload_lds16(gsrc[1] + kb_, &lds[buf_][loff[1]]);                      \
    gload_lds16(gsrc[2] + kb_, &lds[buf_][loff[2]]); }

  i32x16 acc[2][2] = {};

  STAGE(0, 0); STAGE(1, 1);               // 6 per-wave loads in flight

#define TILE(T_, RB_, SB_, VMTOK, DOSTG)                                    \
  {                                                                         \
    VMTOK                                                                   \
    __builtin_amdgcn_s_barrier();                                           \
    asm volatile("" ::: "memory");                                          \
    if (DOSTG) STAGE((T_) + 2, SB_)                                         \
    const char* base_ = &lds[RB_][0];                                       \
    i32x4 aF[2][2], bF[2][2];                                               \
    _Pragma("unroll") for (int mi = 0; mi < 2; ++mi)                        \
      _Pragma("unroll") for (int ks = 0; ks < 2; ++ks)                      \
        aF[mi][ks] = *(const i32x4*)(base_ + ((wr*2+mi)*2+ks)*1024 + l16);  \
    _Pragma("unroll") for (int ni = 0; ni < 2; ++ni)                        \
      _Pragma("unroll") for (int ks = 0; ks < 2; ++ks)                      \
        bF[ni][ks] = *(const i32x4*)(base_ + 16384 + ((wc*2+ni)*2+ks)*1024 + l16); \
    __builtin_amdgcn_s_setprio(1);                                          \
    _Pragma("unroll") for (int ks = 0; ks < 2; ++ks)                        \
      _Pragma("unroll") for (int mi = 0; mi < 2; ++mi)                      \
        _Pragma("unroll") for (int ni = 0; ni < 2; ++ni)                    \
          acc[mi][ni] = __builtin_amdgcn_mfma_i32_32x32x32_i8(              \
              aF[mi][ks], bF[ni][ks], acc[mi][ni], 0, 0, 0);                \
    __builtin_amdgcn_s_setprio(0);                                          \
  }

#define VM3  asm volatile("s_waitcnt vmcnt(3)" ::: "memory");
#define VM0  asm volatile("s_waitcnt vmcnt(0)" ::: "memory");

  for (int t = 0; t < 30; t += 3) {       // tiles 0..29, static ring-3 idx
    TILE(t,     0, 2, VM3, 1);            // read buf0, stage t+2 -> buf2
    TILE(t + 1, 1, 0, VM3, 1);            // read buf1, stage t+3 -> buf0
    TILE(t + 2, 2, 1, VM3, 1);            // read buf2, stage t+4 -> buf1
  }
  TILE(30, 0, 0, VM3, 0);                 // tile 31's 3 loads stay in flight
  TILE(31, 1, 0, VM0, 0);                 // queue empties (last tile only)
#undef TILE
#undef STAGE
#undef VM3
#undef VM0

  // epilogue: C/D mapping col = lane&31, row = (r&3) + 8*(r>>2) + 4*(lane>>5)
  const int lhi = (l >> 5) * 4, lcol = l & 31;
  float bc[2];
  #pragma unroll
  for (int ni = 0; ni < 2; ++ni)
    bc[ni] = bias[bn * 128 + wc * 64 + ni * 32 + lcol];

  #pragma unroll
  for (int mi = 0; mi < 2; ++mi) {
    const int rb = bm * 256 + wr * 64 + mi * 32 + lhi;
    #pragma unroll
    for (int r = 0; r < 16; ++r) {
      const int   row = rb + (r & 3) + 8 * (r >> 2);
      const float sv  = wsc * xs[row];
      #pragma unroll
      for (int ni = 0; ni < 2; ++ni) {
        const int col = bn * 128 + wc * 64 + ni * 32 + lcol;
        out[(size_t)row * Ndim + col] = (float)acc[mi][ni][r] * sv + bc[ni];
      }
    }
  }
}

// ---------------- launch -----------------------------------------------------
extern "C" void kernel_launch(void* const* d_in, const int* in_sizes, int n_in,
                              void* d_out, int out_size, void* d_ws, size_t ws_size,
                              hipStream_t stream) {
  const float* x    = (const float*)d_in[0];
  const float* wgt  = (const float*)d_in[1];
  const float* bias = (const float*)d_in[2];
  float* out = (float*)d_out;

  float* ws_f = (float*)d_ws;
  float* part = ws_f + 64;          // 256 floats
  float* xs   = ws_f + 1024;        // 16384 floats
  char*  wq   = (char*)(ws_f + 20480);          // 4 MiB packed, 16B-aligned
  char*  xq   = wq + (size_t)WELEMS;            // 32 MiB packed, 16B-aligned

  hipLaunchKernelGGL(k_abs_part,  dim3(256),      dim3(256), 0, stream, wgt, part);
  hipLaunchKernelGGL(k_wquant,    dim3(64),       dim3(512), 0, stream, wgt, wq, part);
  hipLaunchKernelGGL(k_xquant,    dim3(Mdim/32),  dim3(512), 0, stream, x, xq, xs);
  hipLaunchKernelGGL(k_gemm,      dim3((Mdim/256)*(Ndim/128)), dim3(512), 0, stream,
                     xq, wq, xs, part, bias, out);
}

// Round 22
// 131.613 us; speedup vs baseline: 1.2094x; 1.0161x over previous
//
#include <hip/hip_runtime.h>
#include <stdint.h>

typedef int i32x4  __attribute__((ext_vector_type(4)));
typedef int i32x16 __attribute__((ext_vector_type(16)));

static constexpr int Mdim   = 16384;     // B*S = 8*2048
static constexpr int Kdim   = 2048;      // D_IN
static constexpr int Ndim   = 2048;      // D_OUT
static constexpr int WELEMS = Ndim * Kdim;   // 4194304

// Fragment-major pack layout (shared by packers and GEMM):
//   chunk(R, c) = 1024 B at base + (R*64 + c)*1024
//   byte l*16 + b of a chunk holds row R*32 + (l&31), k = c*32 + (l>>5)*16 + b

// ---------------- async global->LDS (16B per lane, lane-ordered dest) -------
__device__ __forceinline__ void gload_lds16(const void* g, void* l) {
  __builtin_amdgcn_global_load_lds(
      (const __attribute__((address_space(1))) void*)g,
      (__attribute__((address_space(3))) void*)l,
      16, 0, 0);
}

// ---------------- K1: partial sums of |w| -----------------------------------
__global__ void k_abs_part(const float* __restrict__ w, float* __restrict__ part) {
  const float4* w4 = (const float4*)w;
  float s = 0.f;
  int idx = blockIdx.x * 256 + threadIdx.x;
  #pragma unroll 4
  for (int i = idx; i < WELEMS / 4; i += 256 * 256) {
    float4 v = w4[i];
    s += fabsf(v.x) + fabsf(v.y) + fabsf(v.z) + fabsf(v.w);
  }
  #pragma unroll
  for (int off = 32; off > 0; off >>= 1) s += __shfl_down(s, off);
  __shared__ float sm[4];
  if ((threadIdx.x & 63) == 0) sm[threadIdx.x >> 6] = s;
  __syncthreads();
  if (threadIdx.x == 0) part[blockIdx.x] = sm[0] + sm[1] + sm[2] + sm[3];
}

__device__ __forceinline__ int quant4(float4 v, float sc) {
  int a = (int)rintf(v.x / sc); a = a < -128 ? -128 : (a > 127 ? 127 : a);
  int b = (int)rintf(v.y / sc); b = b < -128 ? -128 : (b > 127 ? 127 : b);
  int c = (int)rintf(v.z / sc); c = c < -128 ? -128 : (c > 127 ? 127 : c);
  int d = (int)rintf(v.w / sc); d = d < -128 ? -128 : (d > 127 ? 127 : d);
  return (a & 255) | ((b & 255) << 8) | ((c & 255) << 16) | ((d & 255) << 24);
}

__device__ __forceinline__ int tern4(float4 v, float s) {
  int a = (int)rintf(v.x / s); a = a < -1 ? -1 : (a > 1 ? 1 : a);
  int b = (int)rintf(v.y / s); b = b < -1 ? -1 : (b > 1 ? 1 : b);
  int c = (int)rintf(v.z / s); c = c < -1 ? -1 : (c > 1 ? 1 : c);
  int d = (int)rintf(v.w / s); d = d < -1 ? -1 : (d > 1 ? 1 : d);
  return (a & 255) | ((b & 255) << 8) | ((c & 255) << 16) | ((d & 255) << 24);
}

// LDS row stride for the transpose buffers: 2052 B (513 dwords, odd ->
// bank = (l*513 + k)%32 spreads 32 rows over all 32 banks; <=2-way = free).
static constexpr int LSTR = 2052;

// ---------------- K3: ternary weight quantize + pack (inlines the scale) ----
__global__ __launch_bounds__(512) void k_wquant(const float* __restrict__ w,
                                                char* __restrict__ wq,
                                                const float* __restrict__ part) {
  __shared__ char sq[32 * LSTR];
  __shared__ float smr[8];
  const int wv = threadIdx.x >> 6;       // 0..7
  const int l  = threadIdx.x & 63;

  // ---- inline scale = mean(|w|): reduce part[0..255] ----
  float ps = (threadIdx.x < 256) ? part[threadIdx.x] : 0.f;
  #pragma unroll
  for (int off = 32; off > 0; off >>= 1) ps += __shfl_down(ps, off);
  if (l == 0) smr[wv] = ps;
  __syncthreads();
  const float s = (smr[0] + smr[1] + smr[2] + smr[3] +
                   smr[4] + smr[5] + smr[6] + smr[7]) / (float)WELEMS + 1e-8f;

  const int Rg = blockIdx.x;
  #pragma unroll
  for (int it = 0; it < 4; ++it) {
    const int rs = it * 8 + wv;          // row slot 0..31
    const float4* wr = (const float4*)(w + (size_t)(Rg * 32 + rs) * Kdim);
    #pragma unroll
    for (int c = 0; c < 8; ++c)
      *(int*)(&sq[rs * LSTR + (c * 64 + l) * 4]) = tern4(wr[c * 64 + l], s);
  }
  __syncthreads();
  char* dst = wq + (size_t)Rg * 65536;
  #pragma unroll
  for (int i = 0; i < 8; ++i) {
    const int c = i * 8 + wv;            // chunk 0..63
    int p[4];
    #pragma unroll
    for (int j = 0; j < 4; ++j)
      p[j] = *(const int*)(&sq[(l & 31) * LSTR + c * 32 + (l >> 5) * 16 + j * 4]);
    *(int4*)(dst + c * 1024 + l * 16) = make_int4(p[0], p[1], p[2], p[3]);
  }
}

// ---------------- K4: per-row absmax + int8 quantize + pack -----------------
__global__ __launch_bounds__(512) void k_xquant(const float* __restrict__ x,
                                                char* __restrict__ xq,
                                                float* __restrict__ xs) {
  __shared__ char sq[32 * LSTR];
  const int Rg = blockIdx.x;
  const int wv = threadIdx.x >> 6;       // 0..7
  const int l  = threadIdx.x & 63;

  #pragma unroll
  for (int it = 0; it < 4; ++it) {
    const int rs  = it * 8 + wv;
    const int row = Rg * 32 + rs;
    const float4* xr = (const float4*)(x + (size_t)row * Kdim);
    float4 v[8];
    float  m = 0.f;
    #pragma unroll
    for (int c = 0; c < 8; ++c) {
      v[c] = xr[c * 64 + l];
      m = fmaxf(m, fmaxf(fmaxf(fabsf(v[c].x), fabsf(v[c].y)),
                         fmaxf(fabsf(v[c].z), fabsf(v[c].w))));
    }
    #pragma unroll
    for (int off = 1; off < 64; off <<= 1) m = fmaxf(m, __shfl_xor(m, off));
    m = fmaxf(m, 1e-8f);
    const float sc = m / 127.0f;
    if (l == 0) xs[row] = sc;
    #pragma unroll
    for (int c = 0; c < 8; ++c)
      *(int*)(&sq[rs * LSTR + (c * 64 + l) * 4]) = quant4(v[c], sc);
  }
  __syncthreads();
  char* dst = xq + (size_t)Rg * 65536;
  #pragma unroll
  for (int i = 0; i < 8; ++i) {
    const int c = i * 8 + wv;
    int p[4];
    #pragma unroll
    for (int j = 0; j < 4; ++j)
      p[j] = *(const int*)(&sq[(l & 31) * LSTR + c * 32 + (l >> 5) * 16 + j * 4]);
    *(int4*)(dst + c * 1024 + l * 16) = make_int4(p[0], p[1], p[2], p[3]);
  }
}

// ---------------- K5: int8 MFMA GEMM, 256x128, RING-3, reads-before-barrier -
// out = (scale*xs[m]) * (xq . wq^T) + bias
// Identical to R21 (512 thr = 8 waves 4Mx2N, wave tile 64x64 = acc[2][2],
// ring-3 x 24 KiB, vmcnt(3) counted, 2 blocks/CU = 16 waves) EXCEPT the TILE
// body is m201-ordered: {vmcnt(3); bar; ds_reads(t); STAGE(t+2); bar;
// setprio MFMA}.  Reads are issued between the barriers so their latency
// drains during barrier-#2 convergence and under other waves' MFMA (lgkm
// waits sit inside the MFMA region), instead of being exposed right before
// the MFMA cluster.  Cross-wave safety: reads(t) follow a barrier preceded
// by EVERY wave's vmcnt(3) (tile-t DMA globally confirmed); STAGE(t+2)
// targets buf[(t-1)%3], whose reads were consumed by MFMA(t-1) lgkm waits
// before any wave reached barrier #1 of tile t.
__global__ __launch_bounds__(512, 4) void k_gemm(
    const char* __restrict__ xq, const char* __restrict__ wq,
    const float* __restrict__ xs, const float* __restrict__ scal_part,
    const float* __restrict__ bias, float* __restrict__ out) {
  __shared__ __attribute__((aligned(128))) char lds[3][24576];

  // XCD-aware bijective swizzle: 1024 blocks, 1024 % 8 == 0.
  const int hw  = blockIdx.x;
  const int lin = (hw & 7) * 128 + (hw >> 3);
  const int bm  = lin >> 4;               // 64 M-tiles (256 rows)
  const int bn  = lin & 15;               // 16 N-tiles (128 cols)

  const int tid = threadIdx.x;
  const int w   = tid >> 6;               // wave 0..7
  const int l   = tid & 63;
  const int wr  = w >> 1, wc = w & 1;     // 4 x 2 wave grid
  const int l16 = l * 16;

  // scale = mean(|w|): in-wave reduce of part[256] (4 vals/lane)
  float ps = scal_part[l] + scal_part[l + 64] + scal_part[l + 128] + scal_part[l + 192];
  #pragma unroll
  for (int off = 32; off > 0; off >>= 1) ps += __shfl_down(ps, off);
  const float wsc = __shfl(ps, 0) / (float)WELEMS;

  // staging map: q = w*3+j over 24 chunks = [A: rg 0..7 x ks 0,1][B: rg 0..3 x ks 0,1]
  const char* gsrc[3];
  int         loff[3];
  #pragma unroll
  for (int j = 0; j < 3; ++j) {
    const int q = w * 3 + j;             // wave-uniform
    if (q < 16) {
      const int rg = q >> 1, ks = q & 1;
      gsrc[j] = xq + (size_t)(bm * 8 + rg) * 65536 + ks * 1024 + l16;
      loff[j] = rg * 2048 + ks * 1024;
    } else {
      const int p = q - 16, rg = p >> 1, ks = p & 1;
      gsrc[j] = wq + (size_t)(bn * 4 + rg) * 65536 + ks * 1024 + l16;
      loff[j] = 16384 + rg * 2048 + ks * 1024;
    }
  }

#define STAGE(t_, buf_)                                                   \
  { const size_t kb_ = (size_t)(t_) * 2048;                               \
    gload_lds16(gsrc[0] + kb_, &lds[buf_][loff[0]]);                      \
    gload_lds16(gsrc[1] + kb_, &lds[buf_][loff[1]]);                      \
    gload_lds16(gsrc[2] + kb_, &lds[buf_][loff[2]]); }

  i32x16 acc[2][2] = {};

  STAGE(0, 0); STAGE(1, 1);               // 6 per-wave loads in flight

#define TILE(T_, RB_, SB_, VMTOK, DOSTG)                                    \
  {                                                                         \
    VMTOK                                                                   \
    __builtin_amdgcn_s_barrier();                                           \
    asm volatile("" ::: "memory");                                          \
    const char* base_ = &lds[RB_][0];                                       \
    i32x4 aF[2][2], bF[2][2];                                               \
    _Pragma("unroll") for (int mi = 0; mi < 2; ++mi)                        \
      _Pragma("unroll") for (int ks = 0; ks < 2; ++ks)                      \
        aF[mi][ks] = *(const i32x4*)(base_ + ((wr*2+mi)*2+ks)*1024 + l16);  \
    _Pragma("unroll") for (int ni = 0; ni < 2; ++ni)                        \
      _Pragma("unroll") for (int ks = 0; ks < 2; ++ks)                      \
        bF[ni][ks] = *(const i32x4*)(base_ + 16384 + ((wc*2+ni)*2+ks)*1024 + l16); \
    if (DOSTG) STAGE((T_) + 2, SB_)                                         \
    __builtin_amdgcn_s_barrier();                                           \
    asm volatile("" ::: "memory");                                          \
    __builtin_amdgcn_s_setprio(1);                                          \
    _Pragma("unroll") for (int ks = 0; ks < 2; ++ks)                        \
      _Pragma("unroll") for (int mi = 0; mi < 2; ++mi)                      \
        _Pragma("unroll") for (int ni = 0; ni < 2; ++ni)                    \
          acc[mi][ni] = __builtin_amdgcn_mfma_i32_32x32x32_i8(              \
              aF[mi][ks], bF[ni][ks], acc[mi][ni], 0, 0, 0);                \
    __builtin_amdgcn_s_setprio(0);                                          \
  }

#define VM3  asm volatile("s_waitcnt vmcnt(3)" ::: "memory");
#define VM0  asm volatile("s_waitcnt vmcnt(0)" ::: "memory");

  for (int t = 0; t < 30; t += 3) {       // tiles 0..29, static ring-3 idx
    TILE(t,     0, 2, VM3, 1);            // read buf0, stage t+2 -> buf2
    TILE(t + 1, 1, 0, VM3, 1);            // read buf1, stage t+3 -> buf0
    TILE(t + 2, 2, 1, VM3, 1);            // read buf2, stage t+4 -> buf1
  }
  TILE(30, 0, 0, VM3, 0);                 // tile 31's 3 loads stay in flight
  TILE(31, 1, 0, VM0, 0);                 // queue empties (last tile only)
#undef TILE
#undef STAGE
#undef VM3
#undef VM0

  // epilogue: C/D mapping col = lane&31, row = (r&3) + 8*(r>>2) + 4*(lane>>5)
  const int lhi = (l >> 5) * 4, lcol = l & 31;
  float bc[2];
  #pragma unroll
  for (int ni = 0; ni < 2; ++ni)
    bc[ni] = bias[bn * 128 + wc * 64 + ni * 32 + lcol];

  #pragma unroll
  for (int mi = 0; mi < 2; ++mi) {
    const int rb = bm * 256 + wr * 64 + mi * 32 + lhi;
    #pragma unroll
    for (int r = 0; r < 16; ++r) {
      const int   row = rb + (r & 3) + 8 * (r >> 2);
      const float sv  = wsc * xs[row];
      #pragma unroll
      for (int ni = 0; ni < 2; ++ni) {
        const int col = bn * 128 + wc * 64 + ni * 32 + lcol;
        out[(size_t)row * Ndim + col] = (float)acc[mi][ni][r] * sv + bc[ni];
      }
    }
  }
}

// ---------------- launch -----------------------------------------------------
extern "C" void kernel_launch(void* const* d_in, const int* in_sizes, int n_in,
                              void* d_out, int out_size, void* d_ws, size_t ws_size,
                              hipStream_t stream) {
  const float* x    = (const float*)d_in[0];
  const float* wgt  = (const float*)d_in[1];
  const float* bias = (const float*)d_in[2];
  float* out = (float*)d_out;

  float* ws_f = (float*)d_ws;
  float* part = ws_f + 64;          // 256 floats
  float* xs   = ws_f + 1024;        // 16384 floats
  char*  wq   = (char*)(ws_f + 20480);          // 4 MiB packed, 16B-aligned
  char*  xq   = wq + (size_t)WELEMS;            // 32 MiB packed, 16B-aligned

  hipLaunchKernelGGL(k_abs_part,  dim3(256),      dim3(256), 0, stream, wgt, part);
  hipLaunchKernelGGL(k_wquant,    dim3(64),       dim3(512), 0, stream, wgt, wq, part);
  hipLaunchKernelGGL(k_xquant,    dim3(Mdim/32),  dim3(512), 0, stream, x, xq, xs);
  hipLaunchKernelGGL(k_gemm,      dim3((Mdim/256)*(Ndim/128)), dim3(512), 0, stream,
                     xq, wq, xs, part, bias, out);
}